// Round 15
// baseline (316.401 us; speedup 1.0000x reference)
//
#include <hip/hip_runtime.h>
#include <stdint.h>
#include <math.h>

#define NALPH 128
#define NEMB  128
#define NST   512
#define BATCH 256
#define TLEN  256
#define FANIN 640   // NEMB + NST

// No host/device-divergent preprocessor control flow (R11 lesson).
#define SDOT4(a, b, c) __builtin_amdgcn_sdot4((a), (b), (c), false)
typedef __attribute__((ext_vector_type(4))) int i32x4;

// LDS-only barrier, race-fixed (R18/R19 lessons): ONE asm statement holding
// both s_waitcnt lgkmcnt(0) and s_barrier with a "memory" clobber (s_barrier
// alone is IntrNoMem to LLVM — ds ops would be hoisted across it), plus
// sched_barrier(0) (rule #18). Omits the vmcnt(0) drain: global stores and
// G prefetches stay in flight across the barrier.
#define BAR_LDS() do {                                            \
    asm volatile("s_waitcnt lgkmcnt(0)\n\ts_barrier" ::: "memory"); \
    __builtin_amdgcn_sched_barrier(0);                            \
  } while (0)

// ---------------------------------------------------------------------------
// k_tr — tiny transpose: WfT[e*512+n] = W_in[n*640+e] (W_f part only).
// ---------------------------------------------------------------------------
__global__ __launch_bounds__(128) void k_tr(
    const float* __restrict__ W_in, float* __restrict__ WfT)
{
  int n = blockIdx.x, e = threadIdx.x;
  WfT[e * NST + n] = W_in[(size_t)n * FANIN + e];
}

// ---------------------------------------------------------------------------
// k_prep (896 blocks x 256 thr) — unchanged from R23 (passing):
//  [0,256)    G[tok*512+n] via coalesced WfT reads (bit-identical fp32 fmaf)
//  [256,768)  W_s row-quant -> WsF MFMA B-frag; Sd
//  [768,896)  W_out row-quant -> WoF frag order; So
// Frag formula HW-validated bit-exact by R12/R15/R17/R20.
// ---------------------------------------------------------------------------
__global__ __launch_bounds__(256) void k_prep(
    const float* __restrict__ emb, const float* __restrict__ W_in,
    const float* __restrict__ b_in, const float* __restrict__ W_out,
    const float* __restrict__ WfT,
    float* __restrict__ G, float* __restrict__ Sd,
    int* __restrict__ WoF, float* __restrict__ So,
    int* __restrict__ WsF)
{
  int bid = blockIdx.x, tid = threadIdx.x;
  if (bid < 256) {
    int tok = bid >> 1;                    // uniform per block (scalar loads)
    int n   = ((bid & 1) << 8) + tid;      // lane-consecutive
    const float* eb = emb + tok * NEMB;
    float acc = b_in[n];
#pragma unroll 8
    for (int e = 0; e < NEMB; ++e)
      acc = fmaf(eb[e], WfT[e * NST + n], acc);
    G[tok * NST + n] = acc;
  } else if (bid < 768) {
    int n = bid - 256;                   // W_s row
    __shared__ float smax[128];
    float lw[4]; float m = 0.f;
    if (tid < 128) {
      float4 v = *(const float4*)(W_in + (size_t)n * FANIN + NEMB + tid * 4);
      lw[0] = v.x; lw[1] = v.y; lw[2] = v.z; lw[3] = v.w;
#pragma unroll
      for (int i = 0; i < 4; ++i) m = fmaxf(m, fabsf(lw[i]));
      smax[tid] = m;
    }
    __syncthreads();
    for (int s2 = 64; s2 > 0; s2 >>= 1) {
      if (tid < s2) smax[tid] = fmaxf(smax[tid], smax[tid + s2]);
      __syncthreads();
    }
    float mx = smax[0];
    if (tid < 128) {
      float r = 127.f / mx;
      uint32_t pk = 0;
#pragma unroll
      for (int i = 0; i < 4; ++i) {
        int qv = (int)rintf(lw[i] * r);
        qv = qv < -127 ? -127 : (qv > 127 ? 127 : qv);
        pk |= (uint32_t)(qv & 0xff) << (8 * i);
      }
      int kd = tid;
      int c = kd >> 4, hi = (kd >> 2) & 3, d = kd & 3;
      int lane = hi * 16 + (n & 15), nt = n >> 4;
      WsF[(((nt * 8 + c) * 64) + lane) * 4 + d] = (int)pk;  // MFMA B-frag
    }
    if (tid == 0) Sd[n] = mx / 16129.0f;
  } else {
    int a = bid - 768;                   // W_out row
    __shared__ float smax[128];
    float lw[4]; float m = 0.f;
    if (tid < 128) {
      float4 v = *(const float4*)(W_out + (size_t)a * NST + tid * 4);
      lw[0] = v.x; lw[1] = v.y; lw[2] = v.z; lw[3] = v.w;
#pragma unroll
      for (int i = 0; i < 4; ++i) m = fmaxf(m, fabsf(lw[i]));
      smax[tid] = m;
    }
    __syncthreads();
    for (int s2 = 64; s2 > 0; s2 >>= 1) {
      if (tid < s2) smax[tid] = fmaxf(smax[tid], smax[tid + s2]);
      __syncthreads();
    }
    float mx = smax[0];
    if (tid < 128) {
      float r = 127.f / mx;
      uint32_t pk = 0;
#pragma unroll
      for (int i = 0; i < 4; ++i) {
        int qv = (int)rintf(lw[i] * r);
        qv = qv < -127 ? -127 : (qv > 127 ? 127 : qv);
        pk |= (uint32_t)(qv & 0xff) << (8 * i);
      }
      int kd = tid;
      int c = kd >> 4, hi = (kd >> 2) & 3, d = kd & 3;
      int lane = hi * 16 + (a & 15), ta = a >> 4;
      WoF[(((ta * 8 + c) * 64) + lane) * 4 + d] = (int)pk;  // MFMA B-frag
    }
    if (tid == 0) So[a] = mx / 16129.0f;
  }
}

// ---------------------------------------------------------------------------
// k_rec R24 — FUSED recurrence + output GEMM via wave specialization.
// 256 blocks x 768 thr (12 waves/CU, 3/SIMD):
//  waves 0-7  (rec): R21's proven engine verbatim, but the state goes into a
//             32-slot LDS ring (stride 528 B: 16B-aligned, 8-row bank spread;
//             full-wave b128 reads sit at the inherent 8-phase floor). The
//             per-step GLOBAL qstates store is DELETED (32 MB writes gone).
//  waves 8-11 (out): every 16 steps, consume the PREVIOUS 16-slot chunk:
//             A from ring rows (cb+l15), bytes hi*16+c*64 — exactly the
//             proven k_out_mfma A-pattern; B = WoF frags; D col=l15 (a),
//             row=hi*4+r (t). Write y directly (k_out kernel + 32 MB read
//             + launch deleted). ~4 mfma/block-step average fills rec's
//             ~550-cyc tail (m114 overlap).
// Ring hazard proof: rec at step t writes slot t&31; out (between barriers
// t-1 and t, at t%16==0) reads slots (t-16..t-1)&31 — disjoint; those slots
// are next overwritten at steps t+16..t+31, >=16 barriers after out's reads.
// Slot 31 zero-init = state at t=-1. No barriers after the loop (rec waves
// exit; out waves do the final chunk alone — no hang).
// Integer dots identical to the proven pair -> absmax exactly 0.009765625.
// ---------------------------------------------------------------------------
#define RSTR 528
__global__ __launch_bounds__(768, 1) void k_rec(
    const int* __restrict__ w, const float* __restrict__ G,
    const int* __restrict__ WsF, const float* __restrict__ Sd,
    const int* __restrict__ WoF, const float* __restrict__ So,
    const float* __restrict__ b_out, float* __restrict__ y)
{
  __shared__ __align__(16) signed char ring[32 * RSTR];   // 16.5 KB
  int tid  = threadIdx.x;
  int lane = tid & 63, wv = tid >> 6;      // wv 0..11
  int l15  = lane & 15, hi = lane >> 4;
  int row  = blockIdx.x;
  const int* wr = w + row * TLEN;
  int ow = wv - 8;                          // out-wave index (wv>=8)

  // Persistent per-role state.
  i32x4 Bf[4][8];                           // rec: W_s B-frags (AGPR-friendly)
  float dn = 0.f, g = 0.f;
  i32x4 Bo[2][8];                           // out: W_out B-frags
  float so0 = 0.f, so1 = 0.f, bo0 = 0.f, bo1 = 0.f;

  if (wv < 8) {
    const i32x4* wsf = (const i32x4*)WsF;
#pragma unroll
    for (int q = 0; q < 4; ++q)
#pragma unroll
      for (int c = 0; c < 8; ++c)
        Bf[q][c] = wsf[((size_t)((wv * 4 + q) * 8 + c)) * 64 + lane];
    dn = Sd[tid];
    g  = G[wr[0] * NST + tid];
  } else {
    const i32x4* wf = (const i32x4*)WoF;
#pragma unroll
    for (int c = 0; c < 8; ++c) {
      Bo[0][c] = wf[((size_t)(((ow * 2 + 0) * 8) + c)) * 64 + lane];
      Bo[1][c] = wf[((size_t)(((ow * 2 + 1) * 8) + c)) * 64 + lane];
    }
    int a0 = (ow * 2 + 0) * 16 + l15;
    int a1 = (ow * 2 + 1) * 16 + l15;
    so0 = So[a0]; bo0 = b_out[a0];
    so1 = So[a1]; bo1 = b_out[a1];
  }

  if (tid < NST) ring[31 * RSTR + tid] = 0;   // state at t = -1
  __syncthreads();

  float* yrow = y + (size_t)row * TLEN * NALPH;

  for (int t = 0; t < TLEN; ++t) {
    if (wv < 8) {
      // ---------------- rec waves: one recurrence step ----------------
      int tok_n = (t < TLEN - 1) ? wr[t + 1] : 0;
      float g_n = G[tok_n * NST + tid];     // prefetch; in flight past BAR
      const signed char* prev = ring + ((t - 1) & 31) * RSTR;
      i32x4 A[8];
#pragma unroll
      for (int c = 0; c < 8; ++c)
        A[c] = *(const i32x4*)(prev + c * 64 + hi * 16);
      i32x4 acc0 = {0,0,0,0}, acc1 = {0,0,0,0}, acc2 = {0,0,0,0}, acc3 = {0,0,0,0};
#pragma unroll
      for (int c = 0; c < 8; ++c) {
        acc0 = __builtin_amdgcn_mfma_i32_16x16x64_i8(A[c], Bf[0][c], acc0, 0, 0, 0);
        acc1 = __builtin_amdgcn_mfma_i32_16x16x64_i8(A[c], Bf[1][c], acc1, 0, 0, 0);
        acc2 = __builtin_amdgcn_mfma_i32_16x16x64_i8(A[c], Bf[2][c], acc2, 0, 0, 0);
        acc3 = __builtin_amdgcn_mfma_i32_16x16x64_i8(A[c], Bf[3][c], acc3, 0, 0, 0);
      }
      int vm = (hi & 1) ? ((hi & 2) ? acc3[0] : acc1[0])
                        : ((hi & 2) ? acc2[0] : acc0[0]);
      float a = g + (float)vm * dn;
      a = fminf(fmaxf(a, -15.f), 15.f);
      float e = __expf(2.f * a);            // tanh = 1 - 2/(e^(2a)+1)
      float s = fmaf(-2.f, __builtin_amdgcn_rcpf(e + 1.f), 1.f);
      signed char q8 = (signed char)(int)rintf(s * 127.f);
      ring[(t & 31) * RSTR + tid] = q8;     // LDS only — no global store
      g = g_n;
    } else if ((t & 15) == 0 && t >= 16) {
      // --------------- out waves: previous 16-step chunk ---------------
      int t0 = t - 16;
      int cb = t0 & 31;                     // 16-aligned ring base
      const signed char* abase = ring + (cb + l15) * RSTR + hi * 16;
      i32x4 A[8];
#pragma unroll
      for (int c = 0; c < 8; ++c) A[c] = *(const i32x4*)(abase + c * 64);
      i32x4 p0 = {0,0,0,0}, p1 = {0,0,0,0};
#pragma unroll
      for (int c = 0; c < 8; ++c) {
        p0 = __builtin_amdgcn_mfma_i32_16x16x64_i8(A[c], Bo[0][c], p0, 0, 0, 0);
        p1 = __builtin_amdgcn_mfma_i32_16x16x64_i8(A[c], Bo[1][c], p1, 0, 0, 0);
      }
      int a0 = (ow * 2 + 0) * 16 + l15;
      int a1 = (ow * 2 + 1) * 16 + l15;
#pragma unroll
      for (int r = 0; r < 4; ++r) {
        size_t rb = (size_t)(t0 + hi * 4 + r) * NALPH;
        yrow[rb + a0] = (float)p0[r] * so0 + bo0;
        yrow[rb + a1] = (float)p1[r] * so1 + bo1;
      }
    }
    BAR_LDS();                              // all 12 waves, every step
  }

  // Final chunk (t0 = 240..255) — out waves only; no barriers after loop.
  if (wv >= 8) {
    int t0 = TLEN - 16;
    int cb = t0 & 31;                       // 16
    const signed char* abase = ring + (cb + l15) * RSTR + hi * 16;
    i32x4 A[8];
#pragma unroll
    for (int c = 0; c < 8; ++c) A[c] = *(const i32x4*)(abase + c * 64);
    i32x4 p0 = {0,0,0,0}, p1 = {0,0,0,0};
#pragma unroll
    for (int c = 0; c < 8; ++c) {
      p0 = __builtin_amdgcn_mfma_i32_16x16x64_i8(A[c], Bo[0][c], p0, 0, 0, 0);
      p1 = __builtin_amdgcn_mfma_i32_16x16x64_i8(A[c], Bo[1][c], p1, 0, 0, 0);
    }
    int a0 = (ow * 2 + 0) * 16 + l15;
    int a1 = (ow * 2 + 1) * 16 + l15;
#pragma unroll
    for (int r = 0; r < 4; ++r) {
      size_t rb = (size_t)(t0 + hi * 4 + r) * NALPH;
      yrow[rb + a0] = (float)p0[r] * so0 + bo0;
      yrow[rb + a1] = (float)p1[r] * so1 + bo1;
    }
  }
}
#undef RSTR

// ---------------------------------------------------------------------------
extern "C" void kernel_launch(void* const* d_in, const int* in_sizes, int n_in,
                              void* d_out, int out_size, void* d_ws, size_t ws_size,
                              hipStream_t stream) {
  const int*   w     = (const int*)d_in[0];
  const float* emb   = (const float*)d_in[1];
  const float* W_in  = (const float*)d_in[2];
  const float* b_in  = (const float*)d_in[3];
  const float* W_out = (const float*)d_in[4];
  const float* b_out = (const float*)d_in[5];
  float* y = (float*)d_out;

  // Workspace map (qstates retired — output GEMM fused into k_rec):
  //   [0,256K)     G
  //   [256K,512K)  WfT   (256 KB transposed W_f)
  //   [512K,514K)  Sd
  //   [640K,641K)  So
  //   [704K,768K)  WoF   (64 KB, frag-order — R16 size lesson)
  //   [768K,1024K) WsF   (256 KB, frag-order)
  char* ws = (char*)d_ws;
  float*       G       = (float*)ws;
  float*       WfT     = (float*)(ws + (256 << 10));
  float*       Sd      = (float*)(ws + (512 << 10));
  float*       So      = (float*)(ws + (640 << 10));
  int*         WoF     = (int*)(ws + (704 << 10));
  int*         WsF     = (int*)(ws + (768 << 10));

  k_tr  <<<512, 128, 0, stream>>>(W_in, WfT);
  k_prep<<<896, 256, 0, stream>>>(emb, W_in, b_in, W_out, WfT, G, Sd, WoF, So, WsF);
  k_rec <<<BATCH, 768, 0, stream>>>(w, G, WsF, Sd, WoF, So, b_out, y);
}